// Round 1
// baseline (93.774 us; speedup 1.0000x reference)
//
#include <hip/hip_runtime.h>
#include <math.h>

// Problem constants (from reference)
#define NB    16
#define NH    76
#define NW    76
#define NCELL (NH * NW)      // 5776
#define NCH   32             // 19 + NC
#define NKP   9
#define NCLS  13
#define NT    50
#define NLROW 21             // 2*NK + 3
#define BLOCK 256
#define CPB   ((NCELL + BLOCK - 1) / BLOCK)   // 23 chunks per batch

// 1/(exp(2)-1)
#define INV_EM1 0.15651764274966565f

__device__ __forceinline__ float sigmoidf_(float x) {
    return 1.0f / (1.0f + __expf(-x));
}

__global__ __launch_bounds__(BLOCK) void loss_main(
    const float* __restrict__ out,   // (NB, 32, 76, 76)
    const float* __restrict__ dt,    // (NB, 32, 76, 76)
    const float* __restrict__ tgt,   // (NB, 1050)
    float* __restrict__ partial)     // (NB*CPB,)
{
    __shared__ float sraw[NT * NLROW];   // raw target rows for this batch
    __shared__ float sgtx[NT * NKP];     // gt x * IMW
    __shared__ float sgty[NT * NKP];     // gt y * IMH
    __shared__ int   sgi[NT], sgj[NT], scls[NT];
    __shared__ int   snv;
    __shared__ float swsum[BLOCK / 64];

    const int b   = blockIdx.y;
    const int tid = threadIdx.x;

    // Stage targets (coalesced)
    for (int i = tid; i < NT * NLROW; i += BLOCK)
        sraw[i] = tgt[b * NT * NLROW + i];
    __syncthreads();

    if (tid < NT) {
        sgi[tid] = (int)(sraw[tid * NLROW + 1] * (float)NW);
        sgj[tid] = (int)(sraw[tid * NLROW + 2] * (float)NH);
        int c = (int)sraw[tid * NLROW + 0];
        scls[tid] = min(max(c, 0), NCLS - 1);
    }
    if (tid < NT * NKP) {
        int t = tid / NKP, k = tid - t * NKP;
        sgtx[tid] = sraw[t * NLROW + 1 + 2 * k] * 640.0f;
        sgty[tid] = sraw[t * NLROW + 2 + 2 * k] * 480.0f;
    }
    if (tid == 0) {
        // cumprod(tgt[:,:,1] != 0): number of leading nonzero rows
        int nv = 0;
        while (nv < NT && sraw[nv * NLROW + 1] != 0.0f) nv++;
        snv = nv;
    }
    __syncthreads();

    const int cell = blockIdx.x * BLOCK + tid;
    float total = 0.0f;

    if (cell < NCELL) {
        const int j = cell / NW;
        const int i = cell - j * NW;
        const float fi = (float)i, fj = (float)j;

        const float* ob = out + (size_t)b * NCH * NCELL + cell;
        const float* db = dt  + (size_t)b * NCH * NCELL + cell;

        // Predicted corners in pixel units: px = (cx + i) * (IMW/nW)
        float px[NKP], py[NKP];
        #pragma unroll
        for (int k = 0; k < NKP; k++) {
            float cx = ob[(2 * k)     * NCELL];
            float cy = ob[(2 * k + 1) * NCELL];
            if (k == 0) { cx = sigmoidf_(cx); cy = sigmoidf_(cy); }
            px[k] = (cx + fi) * (640.0f / 76.0f);
            py[k] = (cy + fj) * (480.0f / 76.0f);
        }
        const float conf  = sigmoidf_(ob[18 * NCELL]);
        const float tconf = sigmoidf_(db[18 * NCELL]);

        const int nv = snv;
        float cur = 0.0f;
        int flag = 0, tcls = 0;
        for (int t = 0; t < nv; t++) {
            // scatter inversion: last valid t hitting this cell wins
            if (sgi[t] == i && sgj[t] == j) { flag = 1; tcls = scls[t]; }
            float s = 0.0f;
            #pragma unroll
            for (int k = 0; k < NKP; k++) {
                float dx = sgtx[t * NKP + k] - px[k];   // LDS broadcast
                float dy = sgty[t * NKP + k] - py[k];
                float dist = sqrtf(dx * dx + dy * dy);
                // (exp(2*(1 - dist/80)) - 1) / (e^2 - 1), gated at dist < 80
                float c = (__expf(2.0f - dist * 0.025f) - 1.0f) * INV_EM1;
                s += (dist < 80.0f) ? c : 0.0f;
            }
            cur = fmaxf(cur, s * (1.0f / 9.0f));
        }

        const float cmask = flag ? 5.0f : (cur > 0.6f ? 0.0f : 1.0f);
        const float dcf = conf - tconf;
        total = 0.5f * dcf * dcf * cmask;

        if (flag) {
            // coord loss: 0.5 * sum over 18 channels of (coords - tcoords)^2
            float cl = 0.0f;
            #pragma unroll
            for (int ch = 0; ch < 18; ch++) {
                float a  = ob[ch * NCELL];
                float bb = db[ch * NCELL];
                if (ch < 2) { a = sigmoidf_(a); bb = sigmoidf_(bb); }
                float d = a - bb;
                cl += d * d;
            }
            total += 0.5f * cl;

            // cls loss: -log_softmax over 13 classes at tcls
            float cv[NCLS];
            float mx = -1e30f;
            #pragma unroll
            for (int c2 = 0; c2 < NCLS; c2++) {
                cv[c2] = ob[(19 + c2) * NCELL];
                mx = fmaxf(mx, cv[c2]);
            }
            float se = 0.0f;
            #pragma unroll
            for (int c2 = 0; c2 < NCLS; c2++) se += __expf(cv[c2] - mx);
            float lse = mx + __logf(se);
            total += lse - cv[tcls];
        }
    }

    // Block reduction: wave64 shuffle, then LDS across the 4 waves
    #pragma unroll
    for (int off = 32; off > 0; off >>= 1)
        total += __shfl_down(total, off, 64);
    if ((tid & 63) == 0) swsum[tid >> 6] = total;
    __syncthreads();
    if (tid == 0) {
        float s = 0.0f;
        #pragma unroll
        for (int w = 0; w < BLOCK / 64; w++) s += swsum[w];
        partial[b * CPB + blockIdx.x] = s;
    }
}

__global__ __launch_bounds__(512) void reduce_partial(
    const float* __restrict__ partial, float* __restrict__ outp, int n)
{
    __shared__ float sw[8];
    const int tid = threadIdx.x;
    float v = 0.0f;
    for (int i = tid; i < n; i += 512) v += partial[i];
    #pragma unroll
    for (int off = 32; off > 0; off >>= 1)
        v += __shfl_down(v, off, 64);
    if ((tid & 63) == 0) sw[tid >> 6] = v;
    __syncthreads();
    if (tid == 0) {
        float s = 0.0f;
        #pragma unroll
        for (int w = 0; w < 8; w++) s += sw[w];
        outp[0] = s;
    }
}

extern "C" void kernel_launch(void* const* d_in, const int* in_sizes, int n_in,
                              void* d_out, int out_size, void* d_ws, size_t ws_size,
                              hipStream_t stream) {
    const float* out_p = (const float*)d_in[0];   // output
    const float* dt_p  = (const float*)d_in[1];   // distiled_target
    const float* tgt_p = (const float*)d_in[2];   // target
    float* partial = (float*)d_ws;                // NB*CPB = 368 floats

    dim3 grid(CPB, NB);
    loss_main<<<grid, BLOCK, 0, stream>>>(out_p, dt_p, tgt_p, partial);
    reduce_partial<<<1, 512, 0, stream>>>(partial, (float*)d_out, NB * CPB);
}